// Round 1
// baseline (889.854 us; speedup 1.0000x reference)
//
#include <hip/hip_runtime.h>
#include <hip/hip_bf16.h>
#include <math.h>

#define V_LEAVES 1048576
#define EMB 128
#define DEPTH 20

// 16 lanes per batch element; each lane holds 8 floats (2 x float4) of the
// 128-dim embedding. 256-thread blocks -> 16 elements per block.
__global__ __launch_bounds__(256) void deepwalk_hsm_kernel(
    const float* __restrict__ emb_table,   // [V, 128]
    const float* __restrict__ hsoftmax,    // [V-1, 128]
    const int*   __restrict__ u,           // [B]
    const int*   __restrict__ v,           // [B]
    float*       __restrict__ out,         // [B]
    int batch)
{
    const int tid  = blockIdx.x * blockDim.x + threadIdx.x;
    const int elem = tid >> 4;        // batch element handled by this 16-lane group
    const int sl   = tid & 15;        // sub-lane within the group
    if (elem >= batch) return;

    // Load this group's slice of v's embedding: 8 consecutive floats per lane.
    const int vi = v[elem];
    const float4* vrow = (const float4*)(emb_table + (size_t)vi * EMB);
    const float4 ve0 = vrow[sl * 2 + 0];
    const float4 ve1 = vrow[sl * 2 + 1];

    int node = (V_LEAVES - 1) + u[elem];   // heap index of leaf
    float loss = 0.0f;

#pragma unroll
    for (int d = 0; d < DEPTH; ++d) {
        const bool is_left = (node & 1) != 0;
        const int parent = (node - 1) >> 1;   // same for left/right child

        const float4* hrow = (const float4*)(hsoftmax + (size_t)parent * EMB);
        const float4 h0 = hrow[sl * 2 + 0];
        const float4 h1 = hrow[sl * 2 + 1];

        float p = h0.x * ve0.x + h0.y * ve0.y + h0.z * ve0.z + h0.w * ve0.w
                + h1.x * ve1.x + h1.y * ve1.y + h1.z * ve1.z + h1.w * ve1.w;

        // Reduce the partial dot across the 16-lane group (xor masks < 16
        // keep the butterfly inside the group even with wave64).
        p += __shfl_xor(p, 1, 64);
        p += __shfl_xor(p, 2, 64);
        p += __shfl_xor(p, 4, 64);
        p += __shfl_xor(p, 8, 64);

        // x = sign * dot;  loss += -log_sigmoid(x) = max(-x,0) + log1p(exp(-|x|))
        const float x  = is_left ? p : -p;
        const float ax = fabsf(x);
        loss += fmaxf(-x, 0.0f) + log1pf(__expf(-ax));

        node = parent;
    }

    if (sl == 0) out[elem] = loss;
}

extern "C" void kernel_launch(void* const* d_in, const int* in_sizes, int n_in,
                              void* d_out, int out_size, void* d_ws, size_t ws_size,
                              hipStream_t stream) {
    const float* emb_table = (const float*)d_in[0];
    const float* hsoftmax  = (const float*)d_in[1];
    const int*   u         = (const int*)d_in[2];
    const int*   v         = (const int*)d_in[3];
    float*       out       = (float*)d_out;

    const int batch = in_sizes[2];            // 65536
    const int threads = batch * 16;           // 16 lanes per element
    const int block = 256;
    const int grid = (threads + block - 1) / block;

    deepwalk_hsm_kernel<<<grid, block, 0, stream>>>(
        emb_table, hsoftmax, u, v, out, batch);
}

// Round 2
// 838.737 us; speedup vs baseline: 1.0609x; 1.0609x over previous
//
#include <hip/hip_runtime.h>
#include <hip/hip_bf16.h>
#include <math.h>

#define V_LEAVES 1048576
#define EMB 128
#define DEPTH 20

// 16 lanes per batch element; each lane holds 8 floats (2 x float4) of the
// 128-dim embedding. 256-thread blocks -> 16 elements per block.
// __launch_bounds__(256,4): cap VGPRs at 128 -> 4 waves/SIMD; R0's full
// unroll likely blew past 256 VGPRs (40 hoisted float4 gathers) -> spills.
__global__ __launch_bounds__(256, 4) void deepwalk_hsm_kernel(
    const float* __restrict__ emb_table,   // [V, 128]
    const float* __restrict__ hsoftmax,    // [V-1, 128]
    const int*   __restrict__ u,           // [B]
    const int*   __restrict__ v,           // [B]
    float*       __restrict__ out,         // [B]
    int batch)
{
    const int tid  = blockIdx.x * blockDim.x + threadIdx.x;
    const int elem = tid >> 4;        // batch element handled by this 16-lane group
    const int sl   = tid & 15;        // sub-lane within the group
    if (elem >= batch) return;

    // This group's slice of v's embedding: 8 consecutive floats per lane.
    const int vi = v[elem];
    const float4* vrow = (const float4*)(emb_table + (size_t)vi * EMB);
    const float4 ve0 = vrow[sl * 2 + 0];
    const float4 ve1 = vrow[sl * 2 + 1];

    // n' = heap_index(leaf) + 1 = V + u.  Then for step d (leaf->root):
    //   parent_d   = (n' >> (d+1)) - 1
    //   is_left_d  = ((n' >> d) & 1) == 0
    // All addresses derive from n' alone -> no loop-carried chain.
    const unsigned np = (unsigned)V_LEAVES + (unsigned)u[elem];

    // Prefetch depth 0's row.
    {
        // nothing extra
    }
    unsigned p0 = (np >> 1) - 1u;
    const float4* hrow = (const float4*)(hsoftmax + (size_t)p0 * EMB);
    float4 h0 = hrow[sl * 2 + 0];
    float4 h1 = hrow[sl * 2 + 1];

    float loss = 0.0f;

#pragma unroll 4
    for (int d = 0; d < DEPTH; ++d) {
        const float4 c0 = h0;
        const float4 c1 = h1;

        // Prefetch next depth's row while we reduce this one.
        if (d + 1 < DEPTH) {
            const unsigned pn = (np >> (d + 2)) - 1u;
            const float4* nrow = (const float4*)(hsoftmax + (size_t)pn * EMB);
            h0 = nrow[sl * 2 + 0];
            h1 = nrow[sl * 2 + 1];
        }

        float p = c0.x * ve0.x + c0.y * ve0.y + c0.z * ve0.z + c0.w * ve0.w
                + c1.x * ve1.x + c1.y * ve1.y + c1.z * ve1.z + c1.w * ve1.w;

        // Reduce across the 16-lane group (xor masks < 16 stay in-group).
        p += __shfl_xor(p, 1, 64);
        p += __shfl_xor(p, 2, 64);
        p += __shfl_xor(p, 4, 64);
        p += __shfl_xor(p, 8, 64);

        const bool is_left = ((np >> d) & 1u) == 0u;
        const float x  = is_left ? p : -p;
        const float ax = fabsf(x);
        loss += fmaxf(-x, 0.0f) + log1pf(__expf(-ax));
    }

    if (sl == 0) out[elem] = loss;
}

extern "C" void kernel_launch(void* const* d_in, const int* in_sizes, int n_in,
                              void* d_out, int out_size, void* d_ws, size_t ws_size,
                              hipStream_t stream) {
    const float* emb_table = (const float*)d_in[0];
    const float* hsoftmax  = (const float*)d_in[1];
    const int*   u         = (const int*)d_in[2];
    const int*   v         = (const int*)d_in[3];
    float*       out       = (float*)d_out;

    const int batch = in_sizes[2];            // 65536
    const int threads = batch * 16;           // 16 lanes per element
    const int block = 256;
    const int grid = (threads + block - 1) / block;

    deepwalk_hsm_kernel<<<grid, block, 0, stream>>>(
        emb_table, hsoftmax, u, v, out, batch);
}